// Round 9
// baseline (339.179 us; speedup 1.0000x reference)
//
#include <hip/hip_runtime.h>
#include <hip/hip_bf16.h>
#include <cmath>

#define Bb 2
#define Tt 2048
#define Hh 8

using u16x8 = __attribute__((ext_vector_type(8))) unsigned short;
using s16x8 = __attribute__((ext_vector_type(8))) short;
using f32x4 = __attribute__((ext_vector_type(4))) float;

__device__ __forceinline__ unsigned short f2bf(float f) {
  __hip_bfloat16 b = __float2bfloat16(f);
  return *reinterpret_cast<unsigned short*>(&b);
}

// async global->LDS, 16B/lane; dest = uniform base + lane*16
#define GLD16(gp, lp)                                                        \
  __builtin_amdgcn_global_load_lds(                                          \
      (const __attribute__((address_space(1))) unsigned int*)(gp),           \
      (__attribute__((address_space(3))) unsigned int*)(lp), 16, 0, 0)

// grid-wide barrier: 512 co-resident blocks, device-scope atomics.
// Each barrier uses its OWN counter; every block adds exactly 1 -> target 512.
__device__ __forceinline__ void gbar(unsigned int* c, unsigned int target) {
  __syncthreads();
  if (threadIdx.x == 0) {
    __threadfence();
    __hip_atomic_fetch_add(c, 1u, __ATOMIC_RELEASE, __HIP_MEMORY_SCOPE_AGENT);
    int guard = 0;
    while (__hip_atomic_load(c, __ATOMIC_ACQUIRE, __HIP_MEMORY_SCOPE_AGENT) <
           target) {
      __builtin_amdgcn_s_sleep(4);
      if (++guard > (1 << 24)) break;   // fail loud (bad output), not hung
    }
    __threadfence();
  }
  __syncthreads();
}

__global__ __launch_bounds__(256, 2) void mega(
    const float* __restrict__ h, const float* __restrict__ rcos,
    const float* __restrict__ rsin,
    const float* __restrict__ W0, const float* __restrict__ W1,
    const float* __restrict__ W2, const float* __restrict__ W3,
    const float* __restrict__ qnw, const float* __restrict__ knw,
    unsigned short* __restrict__ WTall,   // 4*512*512 bf16 [n][k], q,k,v,o
    unsigned short* __restrict__ Hb,      // (4096,512) bf16
    unsigned short* __restrict__ Qw,      // (B,H,T,C)
    unsigned short* __restrict__ Kw,      // (B,H,T,C)
    unsigned short* __restrict__ Vw,      // (B,H,C,T)
    unsigned short* __restrict__ AOw,     // (B,T,H,C)
    float* __restrict__ Out,              // (4096,512) f32
    unsigned int* __restrict__ ctr) {
  __shared__ alignas(16) unsigned short S[13824];   // 27.6 KB union
  int tid = threadIdx.x;
  int bid = blockIdx.x;
  int wave = tid >> 6, lane = tid & 63;
  int ln = lane & 15, qd = lane >> 4;

  // ============ phase 0: weight transpose (blocks 0..255) / h cvt ===========
  if (bid < 256) {
    const float* srcs[4] = {W0, W1, W2, W3};
    const float* src = srcs[bid >> 6];
    unsigned short* dst = WTall + (size_t)(bid >> 6) * 512 * 512;
    int tl = bid & 63;
    int n0 = (tl & 7) * 64, k0 = (tl >> 3) * 64;
    int tx = tid & 63, ty = tid >> 6;
    #pragma unroll
    for (int i = 0; i < 16; ++i) {
      int k = ty * 16 + i;
      S[k * 65 + tx] = f2bf(src[(k0 + k) * 512 + n0 + tx]);
    }
    __syncthreads();
    #pragma unroll
    for (int i = 0; i < 16; ++i) {
      int n = ty * 16 + i;
      dst[(n0 + n) * 512 + k0 + tx] = S[tx * 65 + n];
    }
  } else {
    size_t base = (size_t)(bid - 256) * 8192;
    #pragma unroll
    for (int s = 0; s < 4; ++s) {
      size_t i = base + s * 2048 + tid * 8;
      const float4* g = (const float4*)&h[i];
      float4 f0 = g[0], f1 = g[1];
      u16x8 o = {f2bf(f0.x), f2bf(f0.y), f2bf(f0.z), f2bf(f0.w),
                 f2bf(f1.x), f2bf(f1.y), f2bf(f1.z), f2bf(f1.w)};
      *(u16x8*)&Hb[i] = o;
    }
  }
  gbar(ctr + 0, 512);

  // ============ phase 1: fused QKV GEMM + RMSNorm + RoPE ====================
  // 768 tiles: x = t&31 (m0 = x*128), gh = t>>5 (mat = gh>>3, head = gh&7)
  for (int t = bid; t < 768; t += 512) {
    int m0 = (t & 31) * 128;
    int gh = t >> 5;
    int n0 = gh * 64;
    unsigned short* Al = S;            // [128*64]
    unsigned short* Bl = S + 8192;     // [64*64]
    __syncthreads();                   // S free from previous use

    f32x4 acc[2][4];
    #pragma unroll
    for (int mi = 0; mi < 2; ++mi)
      #pragma unroll
      for (int ni = 0; ni < 4; ++ni) acc[mi][ni] = f32x4{0.f, 0.f, 0.f, 0.f};

    for (int k0 = 0; k0 < 512; k0 += 64) {
      #pragma unroll
      for (int s = 0; s < 4; ++s) {    // A: 16 chunks of 1 KB
        int q = s * 4 + wave;
        int L = q * 64 + lane;
        int row = L >> 3;
        int cb = (L & 7) ^ (row & 7);
        GLD16(&Hb[(size_t)(m0 + row) * 512 + k0 + cb * 8], (char*)Al + q * 1024);
      }
      #pragma unroll
      for (int s = 0; s < 2; ++s) {    // B: 8 chunks
        int q = s * 4 + wave;
        int L = q * 64 + lane;
        int row = L >> 3;
        int cb = (L & 7) ^ (row & 7);
        GLD16(&WTall[(size_t)(n0 + row) * 512 + k0 + cb * 8],
              (char*)Bl + q * 1024);
      }
      __syncthreads();
      #pragma unroll
      for (int half = 0; half < 2; ++half) {
        s16x8 af[2], bfr[4];
        #pragma unroll
        for (int mi = 0; mi < 2; ++mi) {
          int ar = wave * 32 + mi * 16 + ln;
          int cbp = (qd + half * 4) ^ (ar & 7);
          af[mi] = *(const s16x8*)((const char*)Al + ar * 128 + cbp * 16);
        }
        #pragma unroll
        for (int ni = 0; ni < 4; ++ni) {
          int br = ni * 16 + ln;
          int cbp = (qd + half * 4) ^ (br & 7);
          bfr[ni] = *(const s16x8*)((const char*)Bl + br * 128 + cbp * 16);
        }
        #pragma unroll
        for (int mi = 0; mi < 2; ++mi)
          #pragma unroll
          for (int ni = 0; ni < 4; ++ni)
            acc[mi][ni] = __builtin_amdgcn_mfma_f32_16x16x32_bf16(
                af[mi], bfr[ni], acc[mi][ni], 0, 0, 0);
      }
      __syncthreads();
    }

    int mat = gh >> 3, head = gh & 7;
    const float* nw = (mat == 0) ? qnw : knw;
    bool do_rope = (mat < 2);
    int mrow0 = m0 + wave * 32;
    int b = mrow0 >> 11, tb = mrow0 & (Tt - 1);

    #pragma unroll
    for (int mi = 0; mi < 2; ++mi) {
      float vals[4][4];
      #pragma unroll
      for (int ni = 0; ni < 4; ++ni)
        #pragma unroll
        for (int r = 0; r < 4; ++r) vals[ni][r] = acc[mi][ni][r];

      if (do_rope) {
        #pragma unroll
        for (int r = 0; r < 4; ++r) {
          float ss = 0.f;
          #pragma unroll
          for (int ni = 0; ni < 4; ++ni) ss += vals[ni][r] * vals[ni][r];
          ss += __shfl_xor(ss, 1, 64);
          ss += __shfl_xor(ss, 2, 64);
          ss += __shfl_xor(ss, 4, 64);
          ss += __shfl_xor(ss, 8, 64);
          float nrm = rsqrtf(ss * (1.0f / 64.0f) + 1e-6f);
          #pragma unroll
          for (int ni = 0; ni < 4; ++ni) vals[ni][r] *= nrm;
        }
        #pragma unroll
        for (int ni = 0; ni < 4; ++ni) {
          float w = nw[ni * 16 + ln];
          #pragma unroll
          for (int r = 0; r < 4; ++r) vals[ni][r] *= w;
        }
        float res[4][4];
        #pragma unroll
        for (int r = 0; r < 4; ++r) {
          int tt = tb + mi * 16 + qd * 4 + r;
          #pragma unroll
          for (int ni = 0; ni < 4; ++ni) {
            int c = ni * 16 + ln;
            float cs = rcos[tt * 64 + c];
            float sn = rsin[tt * 64 + c];
            float part = vals[ni ^ 2][r];
            float rot = (ni < 2) ? -part : part;
            res[ni][r] = vals[ni][r] * cs + rot * sn;
          }
        }
        #pragma unroll
        for (int ni = 0; ni < 4; ++ni)
          #pragma unroll
          for (int r = 0; r < 4; ++r) vals[ni][r] = res[ni][r];
      }

      if (mat < 2) {   // [t_local 32][c 64] pad 72, wave-private
        unsigned short* Wl = S + wave * 2304;
        #pragma unroll
        for (int ni = 0; ni < 4; ++ni)
          #pragma unroll
          for (int r = 0; r < 4; ++r)
            Wl[(mi * 16 + qd * 4 + r) * 72 + ni * 16 + ln] = f2bf(vals[ni][r]);
      } else {         // V: [c 64][t_local 32] pad 40
        unsigned short* Wl = S + wave * 2560;
        #pragma unroll
        for (int ni = 0; ni < 4; ++ni)
          #pragma unroll
          for (int r = 0; r < 4; ++r)
            Wl[(ni * 16 + ln) * 40 + mi * 16 + qd * 4 + r] = f2bf(vals[ni][r]);
      }
    }

    if (mat < 2) {
      unsigned short* Wl = S + wave * 2304;
      unsigned short* Og =
          ((mat == 0) ? Qw : Kw) + (((size_t)b * Hh + head) * Tt + tb) * 64;
      #pragma unroll
      for (int i = 0; i < 4; ++i) {
        int idx = i * 64 + lane;
        int rr = idx >> 3, cc = (idx & 7) * 8;
        *(u16x8*)&Og[rr * 64 + cc] = *(const u16x8*)&Wl[rr * 72 + cc];
      }
    } else {
      unsigned short* Wl = S + wave * 2560;
      unsigned short* Og = Vw + ((size_t)b * Hh + head) * 64 * 2048 + tb;
      #pragma unroll
      for (int i = 0; i < 4; ++i) {
        int idx = i * 64 + lane;
        int rr = idx >> 2, cc = (idx & 3) * 8;
        *(u16x8*)&Og[(size_t)rr * 2048 + cc] = *(const u16x8*)&Wl[rr * 40 + cc];
      }
    }
  }
  gbar(ctr + 1, 512);

  // ============ phase 2: sliding-window attention ===========================
  {
    int t0 = (bid & 31) * 64;
    int bh = bid >> 5;
    int kb = t0 - 128;
    int q0 = wave * 16;
    const unsigned short* Kg = Kw + (size_t)bh * Tt * 64;
    const unsigned short* Vb = Vw + (size_t)bh * 64 * 2048;
    unsigned short* KP = S;   // [192*72] K tile, then P[64][200]
    __syncthreads();          // S free

    int srow = tid >> 2, scol = (tid & 3) * 16;
    #pragma unroll
    for (int p = 0; p < 3; ++p) {
      int row = p * 64 + srow;
      int kg = kb + row; if (kg < 0) kg = 0;
      const u16x8* gk = (const u16x8*)&Kg[(size_t)kg * 64 + scol];
      u16x8 k0v = gk[0], k1v = gk[1];
      *(u16x8*)&KP[row * 72 + scol] = k0v;
      *(u16x8*)&KP[row * 72 + scol + 8] = k1v;
    }
    const unsigned short* Qg = Qw + ((size_t)bh * Tt + t0 + q0) * 64;
    s16x8 aq0 = *(const s16x8*)&Qg[ln * 64 + qd * 8];
    s16x8 aq1 = *(const s16x8*)&Qg[ln * 64 + 32 + qd * 8];
    __syncthreads();

    f32x4 sf[12];
    #pragma unroll
    for (int nt = 0; nt < 12; ++nt) {
      s16x8 b0 = *(const s16x8*)&KP[(nt * 16 + ln) * 72 + qd * 8];
      s16x8 b1 = *(const s16x8*)&KP[(nt * 16 + ln) * 72 + 32 + qd * 8];
      f32x4 a = {0.f, 0.f, 0.f, 0.f};
      a = __builtin_amdgcn_mfma_f32_16x16x32_bf16(aq0, b0, a, 0, 0, 0);
      a = __builtin_amdgcn_mfma_f32_16x16x32_bf16(aq1, b1, a, 0, 0, 0);
      sf[nt] = a;
    }
    __syncthreads();  // K reads done; reuse as P

    unsigned short* Pl = KP;
    int ok0 = (t0 < 128) ? (128 - t0) : 0;
    #pragma unroll
    for (int r = 0; r < 4; ++r) {
      int lq = q0 + qd * 4 + r;
      float mx = -INFINITY;
      #pragma unroll
      for (int nt = 0; nt < 12; ++nt) {
        int kk = nt * 16 + ln;
        bool valid = (kk > lq) && (kk <= lq + 128) && (kk >= ok0);
        float s = valid ? sf[nt][r] * 0.125f : -INFINITY;
        sf[nt][r] = s;
        mx = fmaxf(mx, s);
      }
      mx = fmaxf(mx, __shfl_xor(mx, 1, 64));
      mx = fmaxf(mx, __shfl_xor(mx, 2, 64));
      mx = fmaxf(mx, __shfl_xor(mx, 4, 64));
      mx = fmaxf(mx, __shfl_xor(mx, 8, 64));
      float sum = 0.f;
      #pragma unroll
      for (int nt = 0; nt < 12; ++nt) {
        float e = __expf(sf[nt][r] - mx);
        sf[nt][r] = e;
        sum += e;
      }
      sum += __shfl_xor(sum, 1, 64);
      sum += __shfl_xor(sum, 2, 64);
      sum += __shfl_xor(sum, 4, 64);
      sum += __shfl_xor(sum, 8, 64);
      float inv = 1.0f / sum;
      #pragma unroll
      for (int nt = 0; nt < 12; ++nt)
        Pl[lq * 200 + nt * 16 + ln] = f2bf(sf[nt][r] * inv);
    }
    // P rows + O-stage region wave-private; V read direct from global

    f32x4 oa[4] = {f32x4{0,0,0,0}, f32x4{0,0,0,0}, f32x4{0,0,0,0},
                   f32x4{0,0,0,0}};
    #pragma unroll
    for (int s = 0; s < 6; ++s) {
      s16x8 ap = *(const s16x8*)&Pl[(q0 + ln) * 200 + s * 32 + qd * 8];
      #pragma unroll
      for (int nt = 0; nt < 4; ++nt) {
        s16x8 bv = *(const s16x8*)&Vb[(size_t)(nt * 16 + ln) * 2048 + kb +
                                      s * 32 + qd * 8];
        oa[nt] = __builtin_amdgcn_mfma_f32_16x16x32_bf16(ap, bv, oa[nt], 0, 0, 0);
      }
    }

    unsigned short* Ow = KP + q0 * 200;
    #pragma unroll
    for (int ni = 0; ni < 4; ++ni)
      #pragma unroll
      for (int r = 0; r < 4; ++r)
        Ow[(qd * 4 + r) * 72 + ni * 16 + ln] = f2bf(oa[ni][r]);
    int b = bh >> 3, hh = bh & 7;
    #pragma unroll
    for (int i = 0; i < 2; ++i) {
      int idx = i * 64 + lane;
      int rr = idx >> 3, cc = (idx & 7) * 8;
      *(u16x8*)&AOw[((size_t)(b * Tt + t0 + q0 + rr) * Hh + hh) * 64 + cc] =
          *(const u16x8*)&Ow[rr * 72 + cc];
    }
  }
  gbar(ctr + 2, 512);

  // ============ phase 3: output GEMM AO @ W_o -> Out (f32) ==================
  {
    int m0 = (bid & 63) * 64;
    int n0 = (bid >> 6) * 64;
    const unsigned short* WTo = WTall + (size_t)3 * 512 * 512;
    unsigned short* Al = S;            // [64*64]
    unsigned short* Bl = S + 4096;
    int wm = wave >> 1, wn = wave & 1;
    __syncthreads();                   // S free

    f32x4 acc[2][2];
    #pragma unroll
    for (int mi = 0; mi < 2; ++mi)
      #pragma unroll
      for (int ni = 0; ni < 2; ++ni) acc[mi][ni] = f32x4{0.f, 0.f, 0.f, 0.f};

    for (int k0 = 0; k0 < 512; k0 += 64) {
      #pragma unroll
      for (int s = 0; s < 2; ++s) {
        int q = s * 4 + wave;
        int L = q * 64 + lane;
        int row = L >> 3;
        int cb = (L & 7) ^ (row & 7);
        GLD16(&AOw[(size_t)(m0 + row) * 512 + k0 + cb * 8], (char*)Al + q * 1024);
        GLD16(&WTo[(size_t)(n0 + row) * 512 + k0 + cb * 8], (char*)Bl + q * 1024);
      }
      __syncthreads();
      #pragma unroll
      for (int half = 0; half < 2; ++half) {
        s16x8 af[2], bfr[2];
        #pragma unroll
        for (int mi = 0; mi < 2; ++mi) {
          int ar = wm * 32 + mi * 16 + ln;
          int cbp = (qd + half * 4) ^ (ar & 7);
          af[mi] = *(const s16x8*)((const char*)Al + ar * 128 + cbp * 16);
        }
        #pragma unroll
        for (int ni = 0; ni < 2; ++ni) {
          int br = wn * 32 + ni * 16 + ln;
          int cbp = (qd + half * 4) ^ (br & 7);
          bfr[ni] = *(const s16x8*)((const char*)Bl + br * 128 + cbp * 16);
        }
        #pragma unroll
        for (int mi = 0; mi < 2; ++mi)
          #pragma unroll
          for (int ni = 0; ni < 2; ++ni)
            acc[mi][ni] = __builtin_amdgcn_mfma_f32_16x16x32_bf16(
                af[mi], bfr[ni], acc[mi][ni], 0, 0, 0);
      }
      __syncthreads();
    }

    #pragma unroll
    for (int mi = 0; mi < 2; ++mi)
      #pragma unroll
      for (int r = 0; r < 4; ++r) {
        int row = m0 + wm * 32 + mi * 16 + qd * 4 + r;
        #pragma unroll
        for (int ni = 0; ni < 2; ++ni)
          Out[(size_t)row * 512 + n0 + wn * 32 + ni * 16 + ln] = acc[mi][ni][r];
      }
  }
}

extern "C" void kernel_launch(void* const* d_in, const int* in_sizes, int n_in,
                              void* d_out, int out_size, void* d_ws,
                              size_t ws_size, hipStream_t stream) {
  const float* h   = (const float*)d_in[0];
  const float* rc  = (const float*)d_in[1];
  const float* rs  = (const float*)d_in[2];
  const float* Wq  = (const float*)d_in[3];
  const float* Wk  = (const float*)d_in[4];
  const float* Wv  = (const float*)d_in[5];
  const float* Wo  = (const float*)d_in[6];
  const float* qnw = (const float*)d_in[7];
  const float* knw = (const float*)d_in[8];

  unsigned short* ws    = (unsigned short*)d_ws;
  unsigned short* WTall = ws;                       // 4*512*512 (q,k,v,o)
  unsigned short* Hb    = WTall + 4 * 512 * 512;
  unsigned short* Qw    = Hb + 2097152;             // (B,H,T,C)
  unsigned short* Kw    = Qw + 2097152;             // (B,H,T,C)
  unsigned short* Vw    = Kw + 2097152;             // (B,H,C,T)
  unsigned short* AOw   = Vw + 2097152;             // (B,T,H,C)
  unsigned int*   ctr   = (unsigned int*)((char*)d_ws + (64u << 20));

  hipMemsetAsync(ctr, 0, 64, stream);
  mega<<<512, 256, 0, stream>>>(h, rc, rs, Wq, Wk, Wv, Wo, qnw, knw,
                                WTall, Hb, Qw, Kw, Vw, AOw,
                                (float*)d_out, ctr);
}

// Round 10
// 113.550 us; speedup vs baseline: 2.9870x; 2.9870x over previous
//
#include <hip/hip_runtime.h>
#include <hip/hip_bf16.h>
#include <cmath>

#define Bb 2
#define Tt 2048
#define Dd 512
#define Hh 8
#define Cc 64
#define WINw 128

using u16x8 = __attribute__((ext_vector_type(8))) unsigned short;
using s16x8 = __attribute__((ext_vector_type(8))) short;
using f32x4 = __attribute__((ext_vector_type(4))) float;

__device__ __forceinline__ unsigned short f2bf(float f) {
  __hip_bfloat16 b = __float2bfloat16(f);
  return *reinterpret_cast<unsigned short*>(&b);
}

// async global->LDS, 16B/lane; dest = uniform base + lane*16 (m97/m104)
#define GLD16(gp, lp)                                                        \
  __builtin_amdgcn_global_load_lds(                                          \
      (const __attribute__((address_space(1))) unsigned int*)(gp),           \
      (__attribute__((address_space(3))) unsigned int*)(lp), 16, 0, 0)

// ---- prep: z<4 -> transpose+cvt weight z into WTall; z==4 -> cvt h ---------
__global__ __launch_bounds__(256) void prep_all(
    const float* __restrict__ s0, const float* __restrict__ s1,
    const float* __restrict__ s2, const float* __restrict__ s3,
    unsigned short* __restrict__ d,
    const float* __restrict__ hsrc, unsigned short* __restrict__ hdst) {
  int tid = threadIdx.x;
  if (blockIdx.z == 4) {
    int gid = ((int)blockIdx.y * 8 + blockIdx.x) * 256 + tid;  // 0..16383
    #pragma unroll
    for (int s = 0; s < 16; ++s) {
      size_t i = ((size_t)s * 16384 + gid) * 8;
      const float4* g = (const float4*)&hsrc[i];
      float4 f0 = g[0], f1 = g[1];
      u16x8 o = {f2bf(f0.x), f2bf(f0.y), f2bf(f0.z), f2bf(f0.w),
                 f2bf(f1.x), f2bf(f1.y), f2bf(f1.z), f2bf(f1.w)};
      *(u16x8*)&hdst[i] = o;
    }
    return;
  }
  __shared__ unsigned short tile[64 * 65];
  const float* srcs[4] = {s0, s1, s2, s3};
  const float* src = srcs[blockIdx.z];
  unsigned short* dst = d + (size_t)blockIdx.z * 512 * 512;
  int n0 = blockIdx.x * 64, k0 = blockIdx.y * 64;
  int tx = tid & 63, ty = tid >> 6;
  #pragma unroll
  for (int i = 0; i < 16; ++i) {
    int k = ty * 16 + i;
    tile[k * 65 + tx] = f2bf(src[(k0 + k) * 512 + n0 + tx]);
  }
  __syncthreads();
  #pragma unroll
  for (int i = 0; i < 16; ++i) {
    int n = ty * 16 + i;
    dst[(n0 + n) * 512 + k0 + tx] = tile[tx * 65 + n];
  }
}

// -------- fused QKV GEMM (128x64 tile, 3 blocks/CU) + RMSNorm + RoPE --------
// grid (32, 24): y = gh in [0,24) -> mat = gh>>3 (Q/K/V), head = gh&7.
// Wave w owns rows [w*32, w*32+32) x all 64 cols (full row in-wave).
// Q,K out: (B,H,T,C). V out: (B,H,C,T).
__global__ __launch_bounds__(256) void qkv_fused(
    const unsigned short* __restrict__ Hb,     // (4096,512) bf16
    const unsigned short* __restrict__ WTall,  // (1536,512) bf16 [n][k]
    const float* __restrict__ qnw, const float* __restrict__ knw,
    const float* __restrict__ rcos, const float* __restrict__ rsin,
    unsigned short* __restrict__ Qw, unsigned short* __restrict__ Kw,
    unsigned short* __restrict__ Vw) {
  __shared__ alignas(16) unsigned short S[12288];   // 24 KB
  unsigned short* Al = S;            // [128*64] 16 chunks of 1024B
  unsigned short* Bl = S + 8192;     // [64*64]   8 chunks
  int tid = threadIdx.x;
  int wave = tid >> 6, lane = tid & 63;
  int ln = lane & 15, qd = lane >> 4;
  int m0 = blockIdx.x * 128;
  int gh = blockIdx.y;               // block-uniform head
  int n0 = gh * 64;

  f32x4 acc[2][4];
  #pragma unroll
  for (int mi = 0; mi < 2; ++mi)
    #pragma unroll
    for (int ni = 0; ni < 4; ++ni) acc[mi][ni] = f32x4{0.f, 0.f, 0.f, 0.f};

  for (int k0 = 0; k0 < 512; k0 += 64) {
    #pragma unroll
    for (int s = 0; s < 4; ++s) {    // A: 16 chunks
      int q = s * 4 + wave;
      int L = q * 64 + lane;
      int row = L >> 3;
      int cb = (L & 7) ^ (row & 7);
      GLD16(&Hb[(size_t)(m0 + row) * 512 + k0 + cb * 8], (char*)Al + q * 1024);
    }
    #pragma unroll
    for (int s = 0; s < 2; ++s) {    // B: 8 chunks
      int q = s * 4 + wave;
      int L = q * 64 + lane;
      int row = L >> 3;
      int cb = (L & 7) ^ (row & 7);
      GLD16(&WTall[(size_t)(n0 + row) * 512 + k0 + cb * 8], (char*)Bl + q * 1024);
    }
    __syncthreads();
    #pragma unroll
    for (int half = 0; half < 2; ++half) {
      s16x8 af[2], bfr[4];
      #pragma unroll
      for (int mi = 0; mi < 2; ++mi) {
        int ar = wave * 32 + mi * 16 + ln;
        int cbp = (qd + half * 4) ^ (ar & 7);
        af[mi] = *(const s16x8*)((const char*)Al + ar * 128 + cbp * 16);
      }
      #pragma unroll
      for (int ni = 0; ni < 4; ++ni) {
        int br = ni * 16 + ln;
        int cbp = (qd + half * 4) ^ (br & 7);
        bfr[ni] = *(const s16x8*)((const char*)Bl + br * 128 + cbp * 16);
      }
      #pragma unroll
      for (int mi = 0; mi < 2; ++mi)
        #pragma unroll
        for (int ni = 0; ni < 4; ++ni)
          acc[mi][ni] = __builtin_amdgcn_mfma_f32_16x16x32_bf16(
              af[mi], bfr[ni], acc[mi][ni], 0, 0, 0);
    }
    __syncthreads();   // final barrier also guards epilogue reuse of S
  }

  int mat = gh >> 3, head = gh & 7;
  const float* nw = (mat == 0) ? qnw : knw;
  bool do_rope = (mat < 2);
  int mrow0 = m0 + wave * 32;
  int b = mrow0 >> 11, tb = mrow0 & (Tt - 1);

  #pragma unroll
  for (int mi = 0; mi < 2; ++mi) {
    float vals[4][4];
    #pragma unroll
    for (int ni = 0; ni < 4; ++ni)
      #pragma unroll
      for (int r = 0; r < 4; ++r) vals[ni][r] = acc[mi][ni][r];

    if (do_rope) {
      #pragma unroll
      for (int r = 0; r < 4; ++r) {
        float ss = 0.f;
        #pragma unroll
        for (int ni = 0; ni < 4; ++ni) ss += vals[ni][r] * vals[ni][r];
        ss += __shfl_xor(ss, 1, 64);
        ss += __shfl_xor(ss, 2, 64);
        ss += __shfl_xor(ss, 4, 64);
        ss += __shfl_xor(ss, 8, 64);
        float nrm = rsqrtf(ss * (1.0f / 64.0f) + 1e-6f);
        #pragma unroll
        for (int ni = 0; ni < 4; ++ni) vals[ni][r] *= nrm;
      }
      #pragma unroll
      for (int ni = 0; ni < 4; ++ni) {
        float w = nw[ni * 16 + ln];
        #pragma unroll
        for (int r = 0; r < 4; ++r) vals[ni][r] *= w;
      }
      float res[4][4];
      #pragma unroll
      for (int r = 0; r < 4; ++r) {
        int t = tb + mi * 16 + qd * 4 + r;
        #pragma unroll
        for (int ni = 0; ni < 4; ++ni) {
          int c = ni * 16 + ln;
          float cs = rcos[t * 64 + c];
          float sn = rsin[t * 64 + c];
          float part = vals[ni ^ 2][r];
          float rot = (ni < 2) ? -part : part;
          res[ni][r] = vals[ni][r] * cs + rot * sn;
        }
      }
      #pragma unroll
      for (int ni = 0; ni < 4; ++ni)
        #pragma unroll
        for (int r = 0; r < 4; ++r) vals[ni][r] = res[ni][r];
    }

    if (mat < 2) {   // [t_local 32][c 64] pad 72, wave-private
      unsigned short* Wl = S + wave * 2304;
      #pragma unroll
      for (int ni = 0; ni < 4; ++ni)
        #pragma unroll
        for (int r = 0; r < 4; ++r)
          Wl[(mi * 16 + qd * 4 + r) * 72 + ni * 16 + ln] = f2bf(vals[ni][r]);
    } else {         // V: [c 64][t_local 32] pad 40
      unsigned short* Wl = S + wave * 2560;
      #pragma unroll
      for (int ni = 0; ni < 4; ++ni)
        #pragma unroll
        for (int r = 0; r < 4; ++r)
          Wl[(ni * 16 + ln) * 40 + mi * 16 + qd * 4 + r] = f2bf(vals[ni][r]);
    }
  }

  if (mat < 2) {
    unsigned short* Wl = S + wave * 2304;
    unsigned short* Og =
        ((mat == 0) ? Qw : Kw) + (((size_t)b * Hh + head) * Tt + tb) * 64;
    #pragma unroll
    for (int i = 0; i < 4; ++i) {    // 32 rows x 64 = 256 chunks
      int idx = i * 64 + lane;
      int rr = idx >> 3, cc = (idx & 7) * 8;
      *(u16x8*)&Og[rr * 64 + cc] = *(const u16x8*)&Wl[rr * 72 + cc];
    }
  } else {
    unsigned short* Wl = S + wave * 2560;
    unsigned short* Og = Vw + ((size_t)b * Hh + head) * 64 * 2048 + tb;
    #pragma unroll
    for (int i = 0; i < 4; ++i) {    // 64 c-rows x 32 t = 256 chunks
      int idx = i * 64 + lane;
      int rr = idx >> 2, cc = (idx & 3) * 8;
      *(u16x8*)&Og[(size_t)rr * 2048 + cc] = *(const u16x8*)&Wl[rr * 40 + cc];
    }
  }
}

// ---------- MFMA sliding-window attention: 64 queries / block ---------------
// Q,K: (B,H,T,C); V: (B,H,C,T). AO: (B,T,H,C).
// V B-frags read DIRECT from global (row-contiguous 16B/lane; verified R9).
// LDS = 27.6 KB (K tile only, reused as P).
__global__ __launch_bounds__(256) void attn_mfma(
    const unsigned short* __restrict__ Q,
    const unsigned short* __restrict__ K,
    const unsigned short* __restrict__ Vg,
    unsigned short* __restrict__ AO) {
  __shared__ alignas(16) unsigned short KP[192 * 72];  // K tile; then P[64][200]
  int tid = threadIdx.x;
  int wave = tid >> 6, lane = tid & 63;
  int ln = lane & 15, qd = lane >> 4;
  int t0 = blockIdx.x * 64, bh = blockIdx.y;
  int kb = t0 - 128;
  int q0 = wave * 16;

  const unsigned short* Kg = K + (size_t)bh * Tt * 64;
  const unsigned short* Vb = Vg + (size_t)bh * 64 * 2048;

  int srow = tid >> 2, scol = (tid & 3) * 16;
  #pragma unroll
  for (int p = 0; p < 3; ++p) {
    int row = p * 64 + srow;
    int kg = kb + row; if (kg < 0) kg = 0;
    const u16x8* gk = (const u16x8*)&Kg[(size_t)kg * 64 + scol];
    u16x8 k0v = gk[0], k1v = gk[1];
    *(u16x8*)&KP[row * 72 + scol] = k0v;
    *(u16x8*)&KP[row * 72 + scol + 8] = k1v;
  }
  const unsigned short* Qg = Q + ((size_t)bh * Tt + t0 + q0) * 64;
  s16x8 aq0 = *(const s16x8*)&Qg[ln * 64 + qd * 8];
  s16x8 aq1 = *(const s16x8*)&Qg[ln * 64 + 32 + qd * 8];
  __syncthreads();

  f32x4 sf[12];
  #pragma unroll
  for (int nt = 0; nt < 12; ++nt) {
    s16x8 b0 = *(const s16x8*)&KP[(nt * 16 + ln) * 72 + qd * 8];
    s16x8 b1 = *(const s16x8*)&KP[(nt * 16 + ln) * 72 + 32 + qd * 8];
    f32x4 a = {0.f, 0.f, 0.f, 0.f};
    a = __builtin_amdgcn_mfma_f32_16x16x32_bf16(aq0, b0, a, 0, 0, 0);
    a = __builtin_amdgcn_mfma_f32_16x16x32_bf16(aq1, b1, a, 0, 0, 0);
    sf[nt] = a;
  }
  __syncthreads();  // K reads done; safe to overwrite KP with P

  unsigned short* Pl = KP;
  int ok0 = (t0 < 128) ? (128 - t0) : 0;
  #pragma unroll
  for (int r = 0; r < 4; ++r) {
    int lq = q0 + qd * 4 + r;
    float mx = -INFINITY;
    #pragma unroll
    for (int nt = 0; nt < 12; ++nt) {
      int kk = nt * 16 + ln;
      bool valid = (kk > lq) && (kk <= lq + 128) && (kk >= ok0);
      float s = valid ? sf[nt][r] * 0.125f : -INFINITY;
      sf[nt][r] = s;
      mx = fmaxf(mx, s);
    }
    mx = fmaxf(mx, __shfl_xor(mx, 1, 64));
    mx = fmaxf(mx, __shfl_xor(mx, 2, 64));
    mx = fmaxf(mx, __shfl_xor(mx, 4, 64));
    mx = fmaxf(mx, __shfl_xor(mx, 8, 64));
    float sum = 0.f;
    #pragma unroll
    for (int nt = 0; nt < 12; ++nt) {
      float e = __expf(sf[nt][r] - mx);
      sf[nt][r] = e;
      sum += e;
    }
    sum += __shfl_xor(sum, 1, 64);
    sum += __shfl_xor(sum, 2, 64);
    sum += __shfl_xor(sum, 4, 64);
    sum += __shfl_xor(sum, 8, 64);
    float inv = 1.0f / sum;
    #pragma unroll
    for (int nt = 0; nt < 12; ++nt)
      Pl[lq * 200 + nt * 16 + ln] = f2bf(sf[nt][r] * inv);
  }
  // no barrier: P rows + O-stage region are wave-private; V comes from global

  f32x4 oa[4] = {f32x4{0,0,0,0}, f32x4{0,0,0,0}, f32x4{0,0,0,0}, f32x4{0,0,0,0}};
  #pragma unroll
  for (int s = 0; s < 6; ++s) {
    s16x8 ap = *(const s16x8*)&Pl[(q0 + ln) * 200 + s * 32 + qd * 8];
    #pragma unroll
    for (int nt = 0; nt < 4; ++nt) {
      s16x8 bv = *(const s16x8*)&Vb[(size_t)(nt * 16 + ln) * 2048 + kb +
                                    s * 32 + qd * 8];
      oa[nt] = __builtin_amdgcn_mfma_f32_16x16x32_bf16(ap, bv, oa[nt], 0, 0, 0);
    }
  }

  unsigned short* Ow = KP + q0 * 200;
  #pragma unroll
  for (int ni = 0; ni < 4; ++ni)
    #pragma unroll
    for (int r = 0; r < 4; ++r)
      Ow[(qd * 4 + r) * 72 + ni * 16 + ln] = f2bf(oa[ni][r]);
  int b = bh >> 3, h = bh & 7;
  #pragma unroll
  for (int i = 0; i < 2; ++i) {
    int idx = i * 64 + lane;
    int rr = idx >> 3, cc = (idx & 7) * 8;
    *(u16x8*)&AO[((size_t)(b * Tt + t0 + q0 + rr) * Hh + h) * 64 + cc] =
        *(const u16x8*)&Ow[rr * 72 + cc];
  }
}

// ------------- output GEMM (64x64 tile, 2 blocks/CU): AO @ W_o -> f32 -------
__global__ __launch_bounds__(256) void out_gemm(
    const unsigned short* __restrict__ Am,  // (4096,512) bf16
    const unsigned short* __restrict__ WT,  // (512,512) bf16 [n][k]
    float* __restrict__ Out) {              // (4096,512) f32
  __shared__ alignas(16) unsigned short Al[64 * 64];
  __shared__ alignas(16) unsigned short Bl[64 * 64];
  int tid = threadIdx.x;
  int wave = tid >> 6, lane = tid & 63;
  int ln = lane & 15, qd = lane >> 4;
  int wm = wave >> 1, wn = wave & 1;
  int m0 = blockIdx.x * 64, n0 = blockIdx.y * 64;

  f32x4 acc[2][2];
  #pragma unroll
  for (int mi = 0; mi < 2; ++mi)
    #pragma unroll
    for (int ni = 0; ni < 2; ++ni) acc[mi][ni] = f32x4{0.f, 0.f, 0.f, 0.f};

  for (int k0 = 0; k0 < 512; k0 += 64) {
    #pragma unroll
    for (int s = 0; s < 2; ++s) {
      int q = s * 4 + wave;
      int L = q * 64 + lane;
      int row = L >> 3;
      int cb = (L & 7) ^ (row & 7);
      GLD16(&Am[(size_t)(m0 + row) * 512 + k0 + cb * 8], (char*)Al + q * 1024);
      GLD16(&WT[(size_t)(n0 + row) * 512 + k0 + cb * 8], (char*)Bl + q * 1024);
    }
    __syncthreads();
    #pragma unroll
    for (int half = 0; half < 2; ++half) {
      s16x8 af[2], bfr[2];
      #pragma unroll
      for (int mi = 0; mi < 2; ++mi) {
        int ar = wm * 32 + mi * 16 + ln;
        int cbp = (qd + half * 4) ^ (ar & 7);
        af[mi] = *(const s16x8*)((const char*)Al + ar * 128 + cbp * 16);
      }
      #pragma unroll
      for (int ni = 0; ni < 2; ++ni) {
        int br = wn * 32 + ni * 16 + ln;
        int cbp = (qd + half * 4) ^ (br & 7);
        bfr[ni] = *(const s16x8*)((const char*)Bl + br * 128 + cbp * 16);
      }
      #pragma unroll
      for (int mi = 0; mi < 2; ++mi)
        #pragma unroll
        for (int ni = 0; ni < 2; ++ni)
          acc[mi][ni] = __builtin_amdgcn_mfma_f32_16x16x32_bf16(
              af[mi], bfr[ni], acc[mi][ni], 0, 0, 0);
    }
    __syncthreads();
  }

  #pragma unroll
  for (int mi = 0; mi < 2; ++mi)
    #pragma unroll
    for (int r = 0; r < 4; ++r) {
      int row = m0 + wm * 32 + mi * 16 + qd * 4 + r;
      #pragma unroll
      for (int ni = 0; ni < 2; ++ni)
        Out[(size_t)row * 512 + n0 + wn * 32 + ni * 16 + ln] = acc[mi][ni][r];
    }
}

extern "C" void kernel_launch(void* const* d_in, const int* in_sizes, int n_in,
                              void* d_out, int out_size, void* d_ws,
                              size_t ws_size, hipStream_t stream) {
  const float* h   = (const float*)d_in[0];
  const float* rc  = (const float*)d_in[1];
  const float* rs  = (const float*)d_in[2];
  const float* Wq  = (const float*)d_in[3];
  const float* Wk  = (const float*)d_in[4];
  const float* Wv  = (const float*)d_in[5];
  const float* Wo  = (const float*)d_in[6];
  const float* qnw = (const float*)d_in[7];
  const float* knw = (const float*)d_in[8];

  unsigned short* ws    = (unsigned short*)d_ws;
  unsigned short* WTall = ws;                       // 1536*512 (q,k,v contiguous)
  unsigned short* WTo   = WTall + 1536 * 512;       // 512*512
  unsigned short* Hb    = WTo + 512 * 512;          // 4096*512 bf16
  unsigned short* Qw    = Hb + 2097152;             // (B,H,T,C)
  unsigned short* Kw    = Qw + 2097152;             // (B,H,T,C)
  unsigned short* Vw    = Kw + 2097152;             // (B,H,C,T)
  unsigned short* AOw   = Vw + 2097152;             // (B,T,H,C)

  prep_all<<<dim3(8, 8, 5), 256, 0, stream>>>(Wq, Wk, Wv, Wo, WTall, h, Hb);

  qkv_fused<<<dim3(32, 24), 256, 0, stream>>>(Hb, WTall, qnw, knw, rc, rs,
                                              Qw, Kw, Vw);

  attn_mfma<<<dim3(32, 16), 256, 0, stream>>>(Qw, Kw, Vw, AOw);

  out_gemm<<<dim3(64, 8), 256, 0, stream>>>(AOw, WTo, (float*)d_out);
}

// Round 12
// 106.075 us; speedup vs baseline: 3.1975x; 1.0705x over previous
//
#include <hip/hip_runtime.h>
#include <hip/hip_bf16.h>
#include <cmath>

#define Tt 2048
#define Hh 8

using u16x8 = __attribute__((ext_vector_type(8))) unsigned short;
using s16x8 = __attribute__((ext_vector_type(8))) short;
using f32x4 = __attribute__((ext_vector_type(4))) float;

__device__ __forceinline__ unsigned short f2bf(float f) {
  __hip_bfloat16 b = __float2bfloat16(f);
  return *reinterpret_cast<unsigned short*>(&b);
}

// async global->LDS, 16B/lane; dest = uniform base + lane*16 (m97/m104)
#define GLD16(gp, lp)                                                        \
  __builtin_amdgcn_global_load_lds(                                          \
      (const __attribute__((address_space(1))) unsigned int*)(gp),           \
      (__attribute__((address_space(3))) unsigned int*)(lp), 16, 0, 0)

// ---- prep: z<4 -> transpose+cvt weight z into WTall; z==4 -> cvt h ---------
__global__ __launch_bounds__(256) void prep_all(
    const float* __restrict__ s0, const float* __restrict__ s1,
    const float* __restrict__ s2, const float* __restrict__ s3,
    unsigned short* __restrict__ d,
    const float* __restrict__ hsrc, unsigned short* __restrict__ hdst) {
  int tid = threadIdx.x;
  if (blockIdx.z == 4) {
    int gid = ((int)blockIdx.y * 8 + blockIdx.x) * 256 + tid;  // 0..16383
    #pragma unroll
    for (int s = 0; s < 16; ++s) {
      size_t i = ((size_t)s * 16384 + gid) * 8;
      const float4* g = (const float4*)&hsrc[i];
      float4 f0 = g[0], f1 = g[1];
      u16x8 o = {f2bf(f0.x), f2bf(f0.y), f2bf(f0.z), f2bf(f0.w),
                 f2bf(f1.x), f2bf(f1.y), f2bf(f1.z), f2bf(f1.w)};
      *(u16x8*)&hdst[i] = o;
    }
    return;
  }
  __shared__ unsigned short tile[64 * 65];
  const float* srcs[4] = {s0, s1, s2, s3};
  const float* src = srcs[blockIdx.z];
  unsigned short* dst = d + (size_t)blockIdx.z * 512 * 512;
  int n0 = blockIdx.x * 64, k0 = blockIdx.y * 64;
  int tx = tid & 63, ty = tid >> 6;
  #pragma unroll
  for (int i = 0; i < 16; ++i) {
    int k = ty * 16 + i;
    tile[k * 65 + tx] = f2bf(src[(k0 + k) * 512 + n0 + tx]);
  }
  __syncthreads();
  #pragma unroll
  for (int i = 0; i < 16; ++i) {
    int n = ty * 16 + i;
    dst[(n0 + n) * 512 + k0 + tx] = tile[tx * 65 + n];
  }
}

// -------- fused QKV GEMM (128x64 tile, dbuf LDS, 1 barrier/K-iter) ----------
// grid (32, 24): y = gh -> mat = gh>>3 (Q/K/V), head = gh&7.
// Q,K out: (B,H,T,C). V out: (B,H,C,T).
__global__ __launch_bounds__(256) void qkv_fused(
    const unsigned short* __restrict__ Hb,     // (4096,512) bf16
    const unsigned short* __restrict__ WTall,  // (1536,512) bf16 [n][k]
    const float* __restrict__ qnw, const float* __restrict__ knw,
    const float* __restrict__ rcos, const float* __restrict__ rsin,
    unsigned short* __restrict__ Qw, unsigned short* __restrict__ Kw,
    unsigned short* __restrict__ Vw) {
  // 48 KB: buffer b at S + b*12288 (A 128x64 = 8192 shorts, B 64x64 = 4096)
  __shared__ alignas(16) unsigned short S[24576];
  int tid = threadIdx.x;
  int wave = tid >> 6, lane = tid & 63;
  int ln = lane & 15, qd = lane >> 4;
  int m0 = blockIdx.x * 128;
  int gh = blockIdx.y;
  int n0 = gh * 64;

  f32x4 acc[2][4];
  #pragma unroll
  for (int mi = 0; mi < 2; ++mi)
    #pragma unroll
    for (int ni = 0; ni < 4; ++ni) acc[mi][ni] = f32x4{0.f, 0.f, 0.f, 0.f};

  auto stage = [&](int k0, int buf) {
    char* Apt = (char*)(S + buf * 12288);
    char* Bpt = (char*)(S + buf * 12288 + 8192);
    #pragma unroll
    for (int s = 0; s < 4; ++s) {    // A: 16 chunks of 1 KB
      int q = s * 4 + wave;
      int L = q * 64 + lane;
      int row = L >> 3;
      int cb = (L & 7) ^ (row & 7);
      GLD16(&Hb[(size_t)(m0 + row) * 512 + k0 + cb * 8], Apt + q * 1024);
    }
    #pragma unroll
    for (int s = 0; s < 2; ++s) {    // B: 8 chunks
      int q = s * 4 + wave;
      int L = q * 64 + lane;
      int row = L >> 3;
      int cb = (L & 7) ^ (row & 7);
      GLD16(&WTall[(size_t)(n0 + row) * 512 + k0 + cb * 8], Bpt + q * 1024);
    }
  };

  stage(0, 0);
  __syncthreads();
  for (int it = 0; it < 8; ++it) {
    int cur = it & 1;
    if (it < 7) stage((it + 1) * 64, cur ^ 1);
    const char* Al = (const char*)(S + cur * 12288);
    const char* Bl = (const char*)(S + cur * 12288 + 8192);
    #pragma unroll
    for (int half = 0; half < 2; ++half) {
      s16x8 af[2], bfr[4];
      #pragma unroll
      for (int mi = 0; mi < 2; ++mi) {
        int ar = wave * 32 + mi * 16 + ln;
        int cbp = (qd + half * 4) ^ (ar & 7);
        af[mi] = *(const s16x8*)(Al + ar * 128 + cbp * 16);
      }
      #pragma unroll
      for (int ni = 0; ni < 4; ++ni) {
        int br = ni * 16 + ln;
        int cbp = (qd + half * 4) ^ (br & 7);
        bfr[ni] = *(const s16x8*)(Bl + br * 128 + cbp * 16);
      }
      #pragma unroll
      for (int mi = 0; mi < 2; ++mi)
        #pragma unroll
        for (int ni = 0; ni < 4; ++ni)
          acc[mi][ni] = __builtin_amdgcn_mfma_f32_16x16x32_bf16(
              af[mi], bfr[ni], acc[mi][ni], 0, 0, 0);
    }
    __syncthreads();   // single drain: loads for it+1 had full MFMA phase
  }

  int mat = gh >> 3, head = gh & 7;
  const float* nw = (mat == 0) ? qnw : knw;
  bool do_rope = (mat < 2);
  int mrow0 = m0 + wave * 32;
  int b = mrow0 >> 11, tb = mrow0 & (Tt - 1);

  #pragma unroll
  for (int mi = 0; mi < 2; ++mi) {
    float vals[4][4];
    #pragma unroll
    for (int ni = 0; ni < 4; ++ni)
      #pragma unroll
      for (int r = 0; r < 4; ++r) vals[ni][r] = acc[mi][ni][r];

    if (do_rope) {
      #pragma unroll
      for (int r = 0; r < 4; ++r) {
        float ss = 0.f;
        #pragma unroll
        for (int ni = 0; ni < 4; ++ni) ss += vals[ni][r] * vals[ni][r];
        ss += __shfl_xor(ss, 1, 64);
        ss += __shfl_xor(ss, 2, 64);
        ss += __shfl_xor(ss, 4, 64);
        ss += __shfl_xor(ss, 8, 64);
        float nrm = rsqrtf(ss * (1.0f / 64.0f) + 1e-6f);
        #pragma unroll
        for (int ni = 0; ni < 4; ++ni) vals[ni][r] *= nrm;
      }
      #pragma unroll
      for (int ni = 0; ni < 4; ++ni) {
        float w = nw[ni * 16 + ln];
        #pragma unroll
        for (int r = 0; r < 4; ++r) vals[ni][r] *= w;
      }
      float res[4][4];
      #pragma unroll
      for (int r = 0; r < 4; ++r) {
        int t = tb + mi * 16 + qd * 4 + r;
        #pragma unroll
        for (int ni = 0; ni < 4; ++ni) {
          int c = ni * 16 + ln;
          float cs = rcos[t * 64 + c];
          float sn = rsin[t * 64 + c];
          float part = vals[ni ^ 2][r];
          float rot = (ni < 2) ? -part : part;
          res[ni][r] = vals[ni][r] * cs + rot * sn;
        }
      }
      #pragma unroll
      for (int ni = 0; ni < 4; ++ni)
        #pragma unroll
        for (int r = 0; r < 4; ++r) vals[ni][r] = res[ni][r];
    }

    if (mat < 2) {   // [t_local 32][c 64] pad 72, wave-private
      unsigned short* Wl = S + wave * 2304;
      #pragma unroll
      for (int ni = 0; ni < 4; ++ni)
        #pragma unroll
        for (int r = 0; r < 4; ++r)
          Wl[(mi * 16 + qd * 4 + r) * 72 + ni * 16 + ln] = f2bf(vals[ni][r]);
    } else {         // V: [c 64][t_local 32] pad 40
      unsigned short* Wl = S + wave * 2560;
      #pragma unroll
      for (int ni = 0; ni < 4; ++ni)
        #pragma unroll
        for (int r = 0; r < 4; ++r)
          Wl[(ni * 16 + ln) * 40 + mi * 16 + qd * 4 + r] = f2bf(vals[ni][r]);
    }
  }

  if (mat < 2) {
    unsigned short* Wl = S + wave * 2304;
    unsigned short* Og =
        ((mat == 0) ? Qw : Kw) + (((size_t)b * Hh + head) * Tt + tb) * 64;
    #pragma unroll
    for (int i = 0; i < 4; ++i) {    // 32 rows x 64 = 256 chunks
      int idx = i * 64 + lane;
      int rr = idx >> 3, cc = (idx & 7) * 8;
      *(u16x8*)&Og[rr * 64 + cc] = *(const u16x8*)&Wl[rr * 72 + cc];
    }
  } else {
    unsigned short* Wl = S + wave * 2560;
    unsigned short* Og = Vw + ((size_t)b * Hh + head) * 64 * 2048 + tb;
    #pragma unroll
    for (int i = 0; i < 4; ++i) {    // 64 c-rows x 32 t = 256 chunks
      int idx = i * 64 + lane;
      int rr = idx >> 2, cc = (idx & 3) * 8;
      *(u16x8*)&Og[(size_t)rr * 2048 + cc] = *(const u16x8*)&Wl[rr * 40 + cc];
    }
  }
}

// ---------- MFMA sliding-window attention (R7 config): 64 queries / block ---
// Q,K: (B,H,T,C); V: (B,H,C,T). AO: (B,T,H,C). 53 KB LDS, 3 blocks/CU.
__global__ __launch_bounds__(256) void attn_mfma(
    const unsigned short* __restrict__ Q,
    const unsigned short* __restrict__ K,
    const unsigned short* __restrict__ Vg,
    unsigned short* __restrict__ AO) {
  __shared__ alignas(16) unsigned short KP[192 * 72];  // K tile; then P[64][200]
  __shared__ alignas(16) unsigned short Vt[64 * 200];  // [c][kk]
  int tid = threadIdx.x;
  int wave = tid >> 6, lane = tid & 63;
  int ln = lane & 15, qd = lane >> 4;
  int t0 = blockIdx.x * 64, bh = blockIdx.y;
  int kb = t0 - 128;
  int q0 = wave * 16;

  const unsigned short* Kg = K + (size_t)bh * Tt * 64;
  const unsigned short* Vb = Vg + (size_t)bh * 64 * 2048;

  int srow = tid >> 2, scol = (tid & 3) * 16;
  #pragma unroll
  for (int p = 0; p < 3; ++p) {
    int row = p * 64 + srow;
    int kg = kb + row; if (kg < 0) kg = 0;
    const u16x8* gk = (const u16x8*)&Kg[(size_t)kg * 64 + scol];
    u16x8 k0v = gk[0], k1v = gk[1];
    *(u16x8*)&KP[row * 72 + scol] = k0v;
    *(u16x8*)&KP[row * 72 + scol + 8] = k1v;
  }
  // V stage: coalesced row copies (V already transposed); kb<0 reads land in
  // preceding K rows -- finite garbage, masked by P=0.
  #pragma unroll
  for (int j = 0; j < 3; ++j)
    #pragma unroll
    for (int it = 0; it < 2; ++it) {
      int idx = it * 256 + tid;
      int row = idx >> 3, ch = (idx & 7) * 8;
      u16x8 v = *(const u16x8*)&Vb[(size_t)row * 2048 + kb + j * 64 + ch];
      *(u16x8*)&Vt[row * 200 + j * 64 + ch] = v;
    }
  const unsigned short* Qg = Q + ((size_t)bh * Tt + t0 + q0) * 64;
  s16x8 aq0 = *(const s16x8*)&Qg[ln * 64 + qd * 8];
  s16x8 aq1 = *(const s16x8*)&Qg[ln * 64 + 32 + qd * 8];
  __syncthreads();

  f32x4 sf[12];
  #pragma unroll
  for (int nt = 0; nt < 12; ++nt) {
    s16x8 b0 = *(const s16x8*)&KP[(nt * 16 + ln) * 72 + qd * 8];
    s16x8 b1 = *(const s16x8*)&KP[(nt * 16 + ln) * 72 + 32 + qd * 8];
    f32x4 a = {0.f, 0.f, 0.f, 0.f};
    a = __builtin_amdgcn_mfma_f32_16x16x32_bf16(aq0, b0, a, 0, 0, 0);
    a = __builtin_amdgcn_mfma_f32_16x16x32_bf16(aq1, b1, a, 0, 0, 0);
    sf[nt] = a;
  }
  __syncthreads();  // K reads done; safe to overwrite KP with P

  unsigned short* Pl = KP;
  int ok0 = (t0 < 128) ? (128 - t0) : 0;
  #pragma unroll
  for (int r = 0; r < 4; ++r) {
    int lq = q0 + qd * 4 + r;
    float mx = -INFINITY;
    #pragma unroll
    for (int nt = 0; nt < 12; ++nt) {
      int kk = nt * 16 + ln;
      bool valid = (kk > lq) && (kk <= lq + 128) && (kk >= ok0);
      float s = valid ? sf[nt][r] * 0.125f : -INFINITY;
      sf[nt][r] = s;
      mx = fmaxf(mx, s);
    }
    mx = fmaxf(mx, __shfl_xor(mx, 1, 64));
    mx = fmaxf(mx, __shfl_xor(mx, 2, 64));
    mx = fmaxf(mx, __shfl_xor(mx, 4, 64));
    mx = fmaxf(mx, __shfl_xor(mx, 8, 64));
    float sum = 0.f;
    #pragma unroll
    for (int nt = 0; nt < 12; ++nt) {
      float e = __expf(sf[nt][r] - mx);
      sf[nt][r] = e;
      sum += e;
    }
    sum += __shfl_xor(sum, 1, 64);
    sum += __shfl_xor(sum, 2, 64);
    sum += __shfl_xor(sum, 4, 64);
    sum += __shfl_xor(sum, 8, 64);
    float inv = 1.0f / sum;
    #pragma unroll
    for (int nt = 0; nt < 12; ++nt)
      Pl[lq * 200 + nt * 16 + ln] = f2bf(sf[nt][r] * inv);
  }
  // no barrier: P rows + O-stage region are wave-private, Vt stable

  f32x4 oa[4] = {f32x4{0,0,0,0}, f32x4{0,0,0,0}, f32x4{0,0,0,0}, f32x4{0,0,0,0}};
  #pragma unroll
  for (int s = 0; s < 6; ++s) {
    s16x8 ap = *(const s16x8*)&Pl[(q0 + ln) * 200 + s * 32 + qd * 8];
    #pragma unroll
    for (int nt = 0; nt < 4; ++nt) {
      s16x8 bv = *(const s16x8*)&Vt[(nt * 16 + ln) * 200 + s * 32 + qd * 8];
      oa[nt] = __builtin_amdgcn_mfma_f32_16x16x32_bf16(ap, bv, oa[nt], 0, 0, 0);
    }
  }

  unsigned short* Ow = KP + q0 * 200;
  #pragma unroll
  for (int ni = 0; ni < 4; ++ni)
    #pragma unroll
    for (int r = 0; r < 4; ++r)
      Ow[(qd * 4 + r) * 72 + ni * 16 + ln] = f2bf(oa[ni][r]);
  int b = bh >> 3, h = bh & 7;
  #pragma unroll
  for (int i = 0; i < 2; ++i) {
    int idx = i * 64 + lane;
    int rr = idx >> 3, cc = (idx & 7) * 8;
    *(u16x8*)&AO[((size_t)(b * Tt + t0 + q0 + rr) * Hh + h) * 64 + cc] =
        *(const u16x8*)&Ow[rr * 72 + cc];
  }
}

// ------------- output GEMM (64x64 tile, dbuf LDS): AO @ W_o -> f32 ----------
__global__ __launch_bounds__(256) void out_gemm(
    const unsigned short* __restrict__ Am,  // (4096,512) bf16
    const unsigned short* __restrict__ WT,  // (512,512) bf16 [n][k]
    float* __restrict__ Out) {              // (4096,512) f32
  // 32 KB: buffer b at S + b*8192 (A 64x64 = 4096 shorts, B same)
  __shared__ alignas(16) unsigned short S[16384];
  int tid = threadIdx.x;
  int wave = tid >> 6, lane = tid & 63;
  int ln = lane & 15, qd = lane >> 4;
  int wm = wave >> 1, wn = wave & 1;
  int m0 = blockIdx.x * 64, n0 = blockIdx.y * 64;

  f32x4 acc[2][2];
  #pragma unroll
  for (int mi = 0; mi < 2; ++mi)
    #pragma unroll
    for (int ni = 0; ni < 2; ++ni) acc[mi][ni] = f32x4{0.f, 0.f, 0.f, 0.f};

  auto stage = [&](int k0, int buf) {
    char* Apt = (char*)(S + buf * 8192);
    char* Bpt = (char*)(S + buf * 8192 + 4096);
    #pragma unroll
    for (int s = 0; s < 2; ++s) {
      int q = s * 4 + wave;
      int L = q * 64 + lane;
      int row = L >> 3;
      int cb = (L & 7) ^ (row & 7);
      GLD16(&Am[(size_t)(m0 + row) * 512 + k0 + cb * 8], Apt + q * 1024);
      GLD16(&WT[(size_t)(n0 + row) * 512 + k0 + cb * 8], Bpt + q * 1024);
    }
  };

  stage(0, 0);
  __syncthreads();
  for (int it = 0; it < 8; ++it) {
    int cur = it & 1;
    if (it < 7) stage((it + 1) * 64, cur ^ 1);
    const char* Al = (const char*)(S + cur * 8192);
    const char* Bl = (const char*)(S + cur * 8192 + 4096);
    #pragma unroll
    for (int half = 0; half < 2; ++half) {
      s16x8 af[2], bfr[2];
      #pragma unroll
      for (int mi = 0; mi < 2; ++mi) {
        int ar = wm * 32 + mi * 16 + ln;
        int cbp = (qd + half * 4) ^ (ar & 7);
        af[mi] = *(const s16x8*)(Al + ar * 128 + cbp * 16);
      }
      #pragma unroll
      for (int ni = 0; ni < 2; ++ni) {
        int br = wn * 32 + ni * 16 + ln;
        int cbp = (qd + half * 4) ^ (br & 7);
        bfr[ni] = *(const s16x8*)(Bl + br * 128 + cbp * 16);
      }
      #pragma unroll
      for (int mi = 0; mi < 2; ++mi)
        #pragma unroll
        for (int ni = 0; ni < 2; ++ni)
          acc[mi][ni] = __builtin_amdgcn_mfma_f32_16x16x32_bf16(
              af[mi], bfr[ni], acc[mi][ni], 0, 0, 0);
    }
    __syncthreads();
  }

  #pragma unroll
  for (int mi = 0; mi < 2; ++mi)
    #pragma unroll
    for (int r = 0; r < 4; ++r) {
      int row = m0 + wm * 32 + mi * 16 + qd * 4 + r;
      #pragma unroll
      for (int ni = 0; ni < 2; ++ni)
        Out[(size_t)row * 512 + n0 + wn * 32 + ni * 16 + ln] = acc[mi][ni][r];
    }
}

extern "C" void kernel_launch(void* const* d_in, const int* in_sizes, int n_in,
                              void* d_out, int out_size, void* d_ws,
                              size_t ws_size, hipStream_t stream) {
  const float* h   = (const float*)d_in[0];
  const float* rc  = (const float*)d_in[1];
  const float* rs  = (const float*)d_in[2];
  const float* Wq  = (const float*)d_in[3];
  const float* Wk  = (const float*)d_in[4];
  const float* Wv  = (const float*)d_in[5];
  const float* Wo  = (const float*)d_in[6];
  const float* qnw = (const float*)d_in[7];
  const float* knw = (const float*)d_in[8];

  unsigned short* ws    = (unsigned short*)d_ws;
  unsigned short* WTall = ws;                       // 1536*512 (q,k,v contiguous)
  unsigned short* WTo   = WTall + 1536 * 512;       // 512*512
  unsigned short* Hb    = WTo + 512 * 512;          // 4096*512 bf16
  unsigned short* Qw    = Hb + 2097152;             // (B,H,T,C)
  unsigned short* Kw    = Qw + 2097152;             // (B,H,T,C)
  unsigned short* Vw    = Kw + 2097152;             // (B,H,C,T)
  unsigned short* AOw   = Vw + 2097152;             // (B,T,H,C)

  prep_all<<<dim3(8, 8, 5), 256, 0, stream>>>(Wq, Wk, Wv, Wo, WTall, h, Hb);

  qkv_fused<<<dim3(32, 24), 256, 0, stream>>>(Hb, WTall, qnw, knw, rc, rs,
                                              Qw, Kw, Vw);

  attn_mfma<<<dim3(32, 16), 256, 0, stream>>>(Qw, Kw, Vw, AOw);

  out_gemm<<<dim3(64, 8), 256, 0, stream>>>(AOw, WTo, (float*)d_out);
}